// Round 6
// baseline (278.964 us; speedup 1.0000x reference)
//
#include <hip/hip_runtime.h>
#include <hip/hip_bf16.h>
#include <hip/hip_fp16.h>
#include <math.h>

// Problem: h = z @ W + b  (z [N,256] fp32, W [256,256] fp32, b [256])
//          out[e] = sigmoid(dot(h[src[e]], h[dst[e]]))  for E edges
// N = 100000, E = 300000, D = 256.
//
// R6: GEMM pipelined on BOTH streams. R5 analysis: VGPR(108)+AGPR(64)=172
// unified -> 2 waves/SIMD; un-prefetched B-frag loads stalled every kb.
// Now: A raw (HBM) and B frags (L2-hot packed W) both prefetched kb+1
// during kb's MFMA block; register ping-pong via unroll 2. Budget ~210
// unified regs (must stay <=256 or waves/SIMD drops to 1).
// h stored fp16 (absmax 0.0078 with 0.02 threshold). 3-term split-bf16
// MFMA (zh*Wh + zh*Wl + zl*Wh) for ~fp32 GEMM accuracy.

#define D_DIM 256
#define BM 64

typedef __attribute__((ext_vector_type(8))) short bf16x8;
typedef __attribute__((ext_vector_type(4))) float f32x4;

__device__ bf16x8 g_Wh[8 * 256 * 4];   // [kb][n][qd] -> 16B frag, 128 KB
__device__ bf16x8 g_Wl[8 * 256 * 4];

__device__ inline unsigned short bf16_rn(float x) {
  unsigned u = __builtin_bit_cast(unsigned, x);
  unsigned r = u + 0x7FFFu + ((u >> 16) & 1u);
  return (unsigned short)(r >> 16);
}
__device__ inline float bf16_f(unsigned short s) {
  return __builtin_bit_cast(float, (unsigned)s << 16);
}

__device__ inline void split8(const float4 f0, const float4 f1, bf16x8& hi, bf16x8& lo) {
  float v[8] = {f0.x, f0.y, f0.z, f0.w, f1.x, f1.y, f1.z, f1.w};
#pragma unroll
  for (int j = 0; j < 8; j++) {
    unsigned short hb = bf16_rn(v[j]);
    hi[j] = (short)hb;
    lo[j] = (short)bf16_rn(v[j] - bf16_f(hb));
  }
}

// 8192 threads: t -> (kb, qd, n), n fastest => coalesced row reads of W.
__global__ __launch_bounds__(256) void pack_w_kernel(const float* __restrict__ W) {
  int t = blockIdx.x * 256 + threadIdx.x;   // 0..8191
  int kb = t >> 10;
  int qd = (t >> 8) & 3;
  int n  = t & 255;
  float v[8];
#pragma unroll
  for (int j = 0; j < 8; j++)
    v[j] = W[(size_t)(kb * 32 + qd * 8 + j) * D_DIM + n];
  bf16x8 hi, lo;
  split8(make_float4(v[0], v[1], v[2], v[3]),
         make_float4(v[4], v[5], v[6], v[7]), hi, lo);
  int fi = (kb * 256 + n) * 4 + qd;
  g_Wh[fi] = hi;
  g_Wl[fi] = lo;
}

__global__ __launch_bounds__(256) void gemm_mfma_kernel(
    const float* __restrict__ z, const float* __restrict__ b,
    __half* __restrict__ h, int nrows) {
  __shared__ __half et[4][16][72];   // wave-private epilogue tiles (9.2 KB)
  const int tid = threadIdx.x;
  const int lane = tid & 63;
  const int wv = tid >> 6;          // wave 0..3 -> cols wv*64 .. +63
  const int fr = lane & 15;
  const int qd = lane >> 4;
  const int row0 = blockIdx.x * BM;

  f32x4 acc[4][4];
#pragma unroll
  for (int i = 0; i < 4; i++)
#pragma unroll
    for (int j = 0; j < 4; j++) acc[i][j] = (f32x4)0.f;

  const float* zp[4];
#pragma unroll
  for (int fm = 0; fm < 4; fm++) {
    int r = row0 + fm * 16 + fr;
    r = r < nrows ? r : (nrows - 1);
    zp[fm] = z + (size_t)r * D_DIM + qd * 8;
  }

  // preload kb=0: raw A (HBM) and B frags (L2-hot)
  float4 a0[4], a1[4];
#pragma unroll
  for (int fm = 0; fm < 4; fm++) {
    a0[fm] = *(const float4*)(zp[fm]);
    a1[fm] = *(const float4*)(zp[fm] + 4);
  }
  bf16x8 bh[4], bl[4];
  {
    const int fbase = (wv * 64) * 4 + qd;
#pragma unroll
    for (int fn = 0; fn < 4; fn++) {
      int fi = fbase + (fn * 16 + fr) * 4;
      bh[fn] = g_Wh[fi];
      bl[fn] = g_Wl[fi];
    }
  }

#pragma unroll 2
  for (int kb = 0; kb < 8; kb++) {
    // convert current A (overlaps in-flight prefetches)
    bf16x8 ah[4], al[4];
#pragma unroll
    for (int fm = 0; fm < 4; fm++) split8(a0[fm], a1[fm], ah[fm], al[fm]);

    // prefetch kb+1: raw A (HBM) + B frags (L2) -- in flight across MFMAs
    float4 na0[4], na1[4];
    bf16x8 nbh[4], nbl[4];
    if (kb < 7) {
#pragma unroll
      for (int fm = 0; fm < 4; fm++) {
        const float* p = zp[fm] + (kb + 1) * 32;
        na0[fm] = *(const float4*)(p);
        na1[fm] = *(const float4*)(p + 4);
      }
      const int nfbase = ((kb + 1) * 256 + wv * 64) * 4 + qd;
#pragma unroll
      for (int fn = 0; fn < 4; fn++) {
        int fi = nfbase + (fn * 16 + fr) * 4;
        nbh[fn] = g_Wh[fi];
        nbl[fn] = g_Wl[fi];
      }
    }

#pragma unroll
    for (int fn = 0; fn < 4; fn++) {
#pragma unroll
      for (int fm = 0; fm < 4; fm++) {
        acc[fm][fn] = __builtin_amdgcn_mfma_f32_16x16x32_bf16(ah[fm], bh[fn], acc[fm][fn], 0, 0, 0);
        acc[fm][fn] = __builtin_amdgcn_mfma_f32_16x16x32_bf16(ah[fm], bl[fn], acc[fm][fn], 0, 0, 0);
        acc[fm][fn] = __builtin_amdgcn_mfma_f32_16x16x32_bf16(al[fm], bh[fn], acc[fm][fn], 0, 0, 0);
      }
    }

    if (kb < 7) {
#pragma unroll
      for (int fm = 0; fm < 4; fm++) { a0[fm] = na0[fm]; a1[fm] = na1[fm]; }
#pragma unroll
      for (int fn = 0; fn < 4; fn++) { bh[fn] = nbh[fn]; bl[fn] = nbl[fn]; }
    }
  }

  // Epilogue: C[row=qd*4+r][col=fn*16+fr] -> wave-private LDS -> 16B stores.
  float bias[4];
#pragma unroll
  for (int fn = 0; fn < 4; fn++) bias[fn] = b[wv * 64 + fn * 16 + fr];

#pragma unroll
  for (int fm = 0; fm < 4; fm++) {
#pragma unroll
    for (int fn = 0; fn < 4; fn++)
#pragma unroll
      for (int r = 0; r < 4; r++)
        et[wv][qd * 4 + r][fn * 16 + fr] = __float2half(acc[fm][fn][r] + bias[fn]);
    // same-wave LDS write->read (in-order LDS pipe per wave; verified R4/R5)
#pragma unroll
    for (int it = 0; it < 2; it++) {
      int chunk = it * 64 + lane;     // 0..127
      int rr = chunk >> 3;            // 0..15
      int cc = chunk & 7;             // 16B chunk within 128B wave strip
      float4 v = *(const float4*)(&et[wv][rr][cc * 8]);
      int row = row0 + fm * 16 + rr;
      if (row < nrows)
        *(float4*)(h + (size_t)row * D_DIM + wv * 64 + cc * 8) = v;
    }
  }
}

// 4 edges per 16-lane group; all 16 x 16B loads hoisted (deep MLP).
__global__ __launch_bounds__(256) void edge_dot_kernel(
    const int* __restrict__ ei, const __half* __restrict__ h,
    float* __restrict__ out, int E) {
  int gid = blockIdx.x * blockDim.x + threadIdx.x;
  int g = gid >> 4;
  int lane = gid & 15;
  int ebase = g * 4;
  if (ebase >= E) return;

  float4 sv[4][2], dv[4][2];
  int ec[4];
#pragma unroll
  for (int q = 0; q < 4; q++) {
    int e = ebase + q;
    ec[q] = e < E ? e : (E - 1);
  }
#pragma unroll
  for (int q = 0; q < 4; q++) {
    int s = ei[ec[q]];
    int d = ei[E + ec[q]];
    const float4* sp = (const float4*)(h + (size_t)s * D_DIM);
    const float4* dp = (const float4*)(h + (size_t)d * D_DIM);
#pragma unroll
    for (int c = 0; c < 2; c++) {
      sv[q][c] = sp[c * 16 + lane];
      dv[q][c] = dp[c * 16 + lane];
    }
  }
  float acc[4] = {0.f, 0.f, 0.f, 0.f};
#pragma unroll
  for (int q = 0; q < 4; q++) {
#pragma unroll
    for (int c = 0; c < 2; c++) {
      const __half2* s2 = (const __half2*)&sv[q][c];
      const __half2* d2 = (const __half2*)&dv[q][c];
#pragma unroll
      for (int j = 0; j < 4; j++) {
        float2 a = __half22float2(s2[j]);
        float2 b2 = __half22float2(d2[j]);
        acc[q] += a.x * b2.x + a.y * b2.y;
      }
    }
  }
#pragma unroll
  for (int m = 1; m <= 8; m <<= 1) {
#pragma unroll
    for (int q = 0; q < 4; q++) acc[q] += __shfl_xor(acc[q], m);
  }
  if (lane == 0) {
    if (ebase + 3 < E) {
      float4 o;
      o.x = 1.0f / (1.0f + expf(-acc[0]));
      o.y = 1.0f / (1.0f + expf(-acc[1]));
      o.z = 1.0f / (1.0f + expf(-acc[2]));
      o.w = 1.0f / (1.0f + expf(-acc[3]));
      *(float4*)(out + ebase) = o;
    } else {
#pragma unroll
      for (int q = 0; q < 4; q++)
        if (ebase + q < E) out[ebase + q] = 1.0f / (1.0f + expf(-acc[q]));
    }
  }
}

extern "C" void kernel_launch(void* const* d_in, const int* in_sizes, int n_in,
                              void* d_out, int out_size, void* d_ws, size_t ws_size,
                              hipStream_t stream) {
  const float* z  = (const float*)d_in[0];
  const int*   ei = (const int*)d_in[1];
  const float* W  = (const float*)d_in[2];
  const float* b  = (const float*)d_in[3];
  float* out = (float*)d_out;
  __half* h  = (__half*)d_ws;   // 100000*256*2 = 51.2 MB scratch

  const int nnodes = in_sizes[0] / D_DIM;
  const int E = in_sizes[1] / 2;

  pack_w_kernel<<<32, 256, 0, stream>>>(W);

  dim3 grid_gemm((nnodes + BM - 1) / BM);
  gemm_mfma_kernel<<<grid_gemm, 256, 0, stream>>>(z, b, h, nnodes);

  int groups = (E + 3) / 4;
  dim3 grid_edge(((size_t)groups * 16 + 255) / 256);
  edge_dot_kernel<<<grid_edge, 256, 0, stream>>>(ei, h, out, E);
}